// Round 5
// baseline (422.032 us; speedup 1.0000x reference)
//
#include <hip/hip_runtime.h>

#define DEV __device__ __forceinline__

typedef unsigned short u16;
typedef unsigned int u32;
typedef __attribute__((ext_vector_type(8))) short short8;
typedef __attribute__((ext_vector_type(4))) float f32x4;

DEV u16 f2bf(float f) {
  u32 u = __float_as_uint(f);
  u32 r = (u + 0x7fffu + ((u >> 16) & 1u)) >> 16;
  return (u16)r;
}
DEV float bf2f_s(short s) { return __uint_as_float(((u32)(u16)s) << 16); }

#define NB 8
#define NH 6
#define CTOT 192
#define HW 16384
#define QLD 136    // q/k LDS row stride (u16): 128-pixel K-window + 8 pad
#define VTS 34     // vt LDS per-col stride (u16): 32 ch + 2 pad (break 16-way)

// load 10 input floats (8 outputs + 2 halo cols) of one row, zero-padded
DEV void loadrow10(float* d, const float* __restrict__ in, int ar, int c0) {
  const bool rok = (ar >= 0) && (ar < 128);
  const float* rp = in + ar * 128;
  d[0] = (rok && c0 > 0) ? rp[c0 - 1] : 0.0f;
  float4 f0, f1;
  if (rok) { f0 = *(const float4*)(rp + c0); f1 = *(const float4*)(rp + c0 + 4); }
  else { f0 = make_float4(0.f,0.f,0.f,0.f); f1 = f0; }
  d[1] = f0.x; d[2] = f0.y; d[3] = f0.z; d[4] = f0.w;
  d[5] = f1.x; d[6] = f1.y; d[7] = f1.z; d[8] = f1.w;
  d[9] = (rok && (c0 + 8) < 128) ? rp[c0 + 8] : 0.0f;
}

// ---------------------------------------------------------------------------
// K1 (fused, v2): block = (b, head, 8-row stripe, 64-col half).
//  - depthwise 3x3 conv q(x), k(y), v(y); 8 cols/thread, 3-row register ring
//  - per 2-row phase: stage q,k (K=128 pixels) to LDS -> gram MFMA partials
//  - v transposed via LDS -> vt[b][n][gc]
//  - gram partials reduced in LDS (4 waves -> 1), then one atomicAdd set
// ---------------------------------------------------------------------------
__global__ __launch_bounds__(256, 4) void k1_fused(
    const float* __restrict__ x, const float* __restrict__ y,
    const float* __restrict__ wdw,
    u16* __restrict__ vt, float* __restrict__ gram,
    float* __restrict__ sqq, float* __restrict__ sqk)
{
  const int t   = threadIdx.x;
  const int bx  = blockIdx.x;          // 1536 = ((b*6+cg)*16+rg)*2+chp
  const int chp = bx & 1;
  const int rg  = (bx >> 1) & 15;
  const int cg  = (bx >> 5) % 6;       // head
  const int b   = bx / 192;
  const int cl  = t >> 3;              // channel in head 0..31
  const int colgrp = t & 7;
  const int gc  = cg * 32 + cl;
  const int c0  = chp * 64 + colgrp * 8;
  const int r0  = rg * 8;
  const int bh  = b * NH + cg;
  const int l    = t & 63, w = t >> 6;
  const int arow = l & 15;
  const int koff = w * 32 + ((l >> 4) << 3);

  __shared__ __align__(16) u16 q_lds[32 * QLD];
  __shared__ __align__(16) u16 k_lds[32 * QLD];
  __shared__ __align__(16) u16 vt_lds[2 * 64 * VTS];
  __shared__ __align__(16) float gram_lds[1024];

  *(f32x4*)&gram_lds[t * 4] = (f32x4){0.f, 0.f, 0.f, 0.f};

  const float* __restrict__ xin = x + (((size_t)(b * CTOT + gc)) << 14);
  const float* __restrict__ yin = y + (((size_t)(b * CTOT + gc)) << 14);

  float wq[9], wk[9], wv[9];
#pragma unroll
  for (int i = 0; i < 9; ++i) {
    wq[i] = wdw[gc * 9 + i];
    wk[i] = wdw[(CTOT + gc) * 9 + i];
    wv[i] = wdw[(2 * CTOT + gc) * 9 + i];
  }

  float xb[3][10], yb[3][10];
  loadrow10(xb[0], xin, r0 - 1, c0);
  loadrow10(yb[0], yin, r0 - 1, c0);
  loadrow10(xb[1], xin, r0,     c0);
  loadrow10(yb[1], yin, r0,     c0);

  f32x4 acc[2][2] = {};
  float sq[2] = {0.f, 0.f}, sk[2] = {0.f, 0.f};

#pragma unroll
  for (int ph = 0; ph < 4; ++ph) {
#pragma unroll
    for (int sub = 0; sub < 2; ++sub) {
      const int rr = ph * 2 + sub;
      const int r  = r0 + rr;
      // ring-load the next input row (used as tap dr=2 this iteration)
      loadrow10(xb[(rr + 2) % 3], xin, r + 1, c0);
      loadrow10(yb[(rr + 2) % 3], yin, r + 1, c0);

      float aq[8], ak[8], av[8];
#pragma unroll
      for (int j = 0; j < 8; ++j) { aq[j] = 0.f; ak[j] = 0.f; av[j] = 0.f; }
#pragma unroll
      for (int dr = 0; dr < 3; ++dr) {
        const float* xr = xb[(rr + dr) % 3];
        const float* yr = yb[(rr + dr) % 3];
#pragma unroll
        for (int j = 0; j < 8; ++j)
#pragma unroll
          for (int dc = 0; dc < 3; ++dc) {
            aq[j] = fmaf(wq[dr * 3 + dc], xr[j + dc], aq[j]);
            ak[j] = fmaf(wk[dr * 3 + dc], yr[j + dc], ak[j]);
            av[j] = fmaf(wv[dr * 3 + dc], yr[j + dc], av[j]);
          }
      }
      short8 pq, pk;
#pragma unroll
      for (int j = 0; j < 8; ++j) {
        pq[j] = (short)f2bf(aq[j]);
        pk[j] = (short)f2bf(ak[j]);
      }
      *(short8*)&q_lds[cl * QLD + sub * 64 + colgrp * 8] = pq;
      *(short8*)&k_lds[cl * QLD + sub * 64 + colgrp * 8] = pk;
#pragma unroll
      for (int j = 0; j < 8; ++j)
        vt_lds[sub * 64 * VTS + (colgrp * 8 + j) * VTS + cl] = f2bf(av[j]);
    }
    __syncthreads();

    // gram partial via MFMA over the 128-pixel window + sum-of-squares
    short8 a2[2], b2[2];
#pragma unroll
    for (int tc = 0; tc < 2; ++tc) {
      a2[tc] = *(const short8*)&q_lds[(tc * 16 + arow) * QLD + koff];
      b2[tc] = *(const short8*)&k_lds[(tc * 16 + arow) * QLD + koff];
    }
#pragma unroll
    for (int tc = 0; tc < 2; ++tc)
#pragma unroll
      for (int j = 0; j < 8; ++j) {
        float fa = bf2f_s(a2[tc][j]); sq[tc] = fmaf(fa, fa, sq[tc]);
        float fb = bf2f_s(b2[tc][j]); sk[tc] = fmaf(fb, fb, sk[tc]);
      }
#pragma unroll
    for (int tc = 0; tc < 2; ++tc)
#pragma unroll
      for (int td = 0; td < 2; ++td)
        acc[tc][td] = __builtin_amdgcn_mfma_f32_16x16x32_bf16(a2[tc], b2[td], acc[tc][td], 0, 0, 0);

    // vt store: thread t owns (row sub=t>>7, col=(t>>1)&63, 16-ch half t&1)
    {
      const int sub  = t >> 7;
      const int col  = (t >> 1) & 63;
      const int half = (t & 1) * 16;
      const int r    = r0 + ph * 2 + sub;
      const int base = sub * 64 * VTS + col * VTS + half;
      short8 d0, d1;
#pragma unroll
      for (int j = 0; j < 8; ++j) { d0[j] = (short)vt_lds[base + j]; d1[j] = (short)vt_lds[base + 8 + j]; }
      size_t off = ((size_t)(b * HW + r * 128 + chp * 64 + col)) * CTOT + cg * 32 + half;
      *(short8*)(vt + off)     = d0;
      *(short8*)(vt + off + 8) = d1;
    }
    __syncthreads();
  }

  // block-level gram reduction in LDS, then one global atomicAdd per element
#pragma unroll
  for (int tc = 0; tc < 2; ++tc)
#pragma unroll
    for (int td = 0; td < 2; ++td)
#pragma unroll
      for (int r2 = 0; r2 < 4; ++r2) {
        int c = tc * 16 + (l >> 4) * 4 + r2;
        int d = td * 16 + arow;
        atomicAdd(&gram_lds[c * 32 + d], acc[tc][td][r2]);
      }
  __syncthreads();
#pragma unroll
  for (int i = 0; i < 4; ++i)
    atomicAdd(gram + (size_t)bh * 1024 + t * 4 + i, gram_lds[t * 4 + i]);

#pragma unroll
  for (int tc = 0; tc < 2; ++tc) {
    sq[tc] += __shfl_xor(sq[tc], 16);
    sq[tc] += __shfl_xor(sq[tc], 32);
    sk[tc] += __shfl_xor(sk[tc], 16);
    sk[tc] += __shfl_xor(sk[tc], 32);
  }
  if ((l >> 4) == 0) {
#pragma unroll
    for (int tc = 0; tc < 2; ++tc) {
      atomicAdd(sqq + bh * 32 + tc * 16 + arow, sq[tc]);
      atomicAdd(sqk + bh * 32 + tc * 16 + arow, sk[tc]);
    }
  }
}

// ---------------------------------------------------------------------------
// K2b: logits = gram/(|q||k|)*temp, row-softmax, fold 1x1 proj:
//   W2[b][o][h*32+d] = sum_c wp[o][h*32+c] * A[c][d]  (bf16 out)
// ---------------------------------------------------------------------------
__global__ __launch_bounds__(256) void k2b_w2(
    const float* __restrict__ gram, const float* __restrict__ sqq,
    const float* __restrict__ sqk, const float* __restrict__ wp,
    const float* __restrict__ temp, u16* __restrict__ W2)
{
  __shared__ float Ls[32][33];
  __shared__ float As[32][33];
  __shared__ float wl[192 * 32];
  __shared__ float nq[32], nk[32];
  const int t = threadIdx.x;
  const int bh = blockIdx.x, b = bh / 6, h = bh % 6;
  const float tmp = temp[h];
  if (t < 32) nq[t] = fmaxf(sqrtf(sqq[bh * 32 + t]), 1e-12f);
  else if (t < 64) nk[t - 32] = fmaxf(sqrtf(sqk[bh * 32 + t - 32]), 1e-12f);
  __syncthreads();
#pragma unroll
  for (int i = 0; i < 4; ++i) {
    int idx = i * 256 + t, c = idx >> 5, d = idx & 31;
    Ls[c][d] = gram[(size_t)bh * 1024 + idx] / (nq[c] * nk[d]) * tmp;
  }
  __syncthreads();
  if (t < 32) {
    float m = -1e30f;
#pragma unroll
    for (int d = 0; d < 32; ++d) m = fmaxf(m, Ls[t][d]);
    float s = 0.f;
#pragma unroll
    for (int d = 0; d < 32; ++d) s += expf(Ls[t][d] - m);
    float inv = 1.0f / s;
#pragma unroll
    for (int d = 0; d < 32; ++d) As[t][d] = expf(Ls[t][d] - m) * inv;
  }
  for (int i = 0; i < 24; ++i) {
    int idx = i * 256 + t, o = idx >> 5, c = idx & 31;
    wl[idx] = wp[o * 192 + h * 32 + c];
  }
  __syncthreads();
  for (int i = 0; i < 24; ++i) {
    int idx = i * 256 + t, o = idx >> 5, d = idx & 31;
    float a = 0.f;
#pragma unroll
    for (int c = 0; c < 32; ++c) a = fmaf(wl[o * 32 + c], As[c][d], a);
    W2[((size_t)(b * 192 + o)) * 192 + h * 32 + d] = f2bf(a);
  }
}

// ---------------------------------------------------------------------------
// K3: out[b][o][n] = sum_c W2[b][o][c] * v[b][c][n] via MFMA 16x16x32 bf16.
// A = W2 [o][c] k-contiguous, B = vt [n][c] k-contiguous: direct 16B loads.
// ---------------------------------------------------------------------------
__global__ __launch_bounds__(256) void k3_gemm(
    const u16* __restrict__ W2, const u16* __restrict__ vt,
    float* __restrict__ out)
{
  const int t = threadIdx.x, l = t & 63, w = t >> 6;
  const int bx = blockIdx.x;
  const int b  = bx >> 7, nb = bx & 127;
  const int row = l & 15;
  const int kq  = (l >> 4) * 8;
  const u16* w2b = W2 + (size_t)b * 192 * 192;
  const u16* vtb = vt + ((size_t)b << 14) * 192;
  const int n0 = nb * 128 + w * 32;

  f32x4 acc[12][2] = {};

  for (int ks = 0; ks < 6; ++ks) {
    const int kb = ks * 32 + kq;
    short8 bf[2];
#pragma unroll
    for (int nt = 0; nt < 2; ++nt)
      bf[nt] = *(const short8*)(vtb + (size_t)(n0 + nt * 16 + row) * 192 + kb);
#pragma unroll
    for (int ot = 0; ot < 12; ++ot) {
      short8 af = *(const short8*)(w2b + (size_t)(ot * 16 + row) * 192 + kb);
#pragma unroll
      for (int nt = 0; nt < 2; ++nt)
        acc[ot][nt] = __builtin_amdgcn_mfma_f32_16x16x32_bf16(af, bf[nt], acc[ot][nt], 0, 0, 0);
    }
  }

  float* ob = out + ((size_t)b * 192) * 16384;
#pragma unroll
  for (int ot = 0; ot < 12; ++ot)
#pragma unroll
    for (int nt = 0; nt < 2; ++nt)
#pragma unroll
      for (int rr = 0; rr < 4; ++rr) {
        int o = ot * 16 + (l >> 4) * 4 + rr;
        int n = n0 + nt * 16 + row;
        ob[(size_t)o * 16384 + n] = acc[ot][nt][rr];
      }
}

// ---------------------------------------------------------------------------
extern "C" void kernel_launch(void* const* d_in, const int* in_sizes, int n_in,
                              void* d_out, int out_size, void* d_ws, size_t ws_size,
                              hipStream_t stream)
{
  const float* x    = (const float*)d_in[0];
  const float* y    = (const float*)d_in[1];
  const float* wdw  = (const float*)d_in[2];
  const float* wp   = (const float*)d_in[3];
  const float* temp = (const float*)d_in[4];

  char* ws = (char*)d_ws;
  const size_t VT = (size_t)NB * HW * CTOT * 2;   // 50,331,648 bytes
  u16*   vt   = (u16*)(ws);
  float* gram = (float*)(ws + VT);                       // 48*1024*4 = 196608
  float* sqq  = (float*)(ws + VT + 196608);              // 6144
  float* sqk  = (float*)(ws + VT + 196608 + 6144);       // 6144
  u16*   W2   = (u16*)(ws + VT + 196608 + 12288);        // 8*192*192*2
  float* out  = (float*)d_out;

  hipMemsetAsync(ws + VT, 0, 208896, stream);
  k1_fused<<<1536, 256, 0, stream>>>(x, y, wdw, vt, gram, sqq, sqk);
  k2b_w2<<<48, 256, 0, stream>>>(gram, sqq, sqk, wp, temp, W2);
  k3_gemm<<<1024, 256, 0, stream>>>(W2, vt, out);
}

// Round 6
// 182.850 us; speedup vs baseline: 2.3081x; 2.3081x over previous
//
#include <hip/hip_runtime.h>

#define DEV __device__ __forceinline__

typedef unsigned short u16;
typedef unsigned int u32;
typedef __attribute__((ext_vector_type(8))) short short8;
typedef __attribute__((ext_vector_type(4))) float f32x4;

DEV u16 f2bf(float f) {
  u32 u = __float_as_uint(f);
  u32 r = (u + 0x7fffu + ((u >> 16) & 1u)) >> 16;
  return (u16)r;
}
DEV float bf2f_s(short s) { return __uint_as_float(((u32)(u16)s) << 16); }

#define NB 8
#define NH 6
#define CTOT 192
#define HW 16384
#define QLD 136    // q/k LDS row stride (u16): 128-pixel K-window + 8 pad
#define VTS 34     // vt LDS per-col stride (u16): 32 ch + 2 pad (16-way -> 4-way)

// load 10 input floats (8 outputs + 2 halo cols) of one row, zero-padded
DEV void loadrow10(float* d, const float* __restrict__ in, int ar, int c0) {
  const bool rok = (ar >= 0) && (ar < 128);
  const float* rp = in + ar * 128;
  d[0] = (rok && c0 > 0) ? rp[c0 - 1] : 0.0f;
  float4 f0, f1;
  if (rok) { f0 = *(const float4*)(rp + c0); f1 = *(const float4*)(rp + c0 + 4); }
  else { f0 = make_float4(0.f,0.f,0.f,0.f); f1 = f0; }
  d[1] = f0.x; d[2] = f0.y; d[3] = f0.z; d[4] = f0.w;
  d[5] = f1.x; d[6] = f1.y; d[7] = f1.z; d[8] = f1.w;
  d[9] = (rok && (c0 + 8) < 128) ? rp[c0 + 8] : 0.0f;
}

// ---------------------------------------------------------------------------
// K1 (fused, v3): identical structure to round-5 v2, but WITHOUT the
// __launch_bounds__ min-waves clamp. Round-5's 375us regression was scratch
// spilling (VGPR forced to 64 < ~130 live set; FETCH 283->608MB, WRITE
// 66->490MB). Let the allocator use ~112-130 VGPRs like the no-spill round-4.
//  block = (b, head, 8-row stripe, 64-col half), 8 cols/thread,
//  3-row register ring, per-2-row-phase gram MFMA, LDS gram reduction.
// ---------------------------------------------------------------------------
__global__ __launch_bounds__(256) void k1_fused(
    const float* __restrict__ x, const float* __restrict__ y,
    const float* __restrict__ wdw,
    u16* __restrict__ vt, float* __restrict__ gram,
    float* __restrict__ sqq, float* __restrict__ sqk)
{
  const int t   = threadIdx.x;
  const int bx  = blockIdx.x;          // 1536 = ((b*6+cg)*16+rg)*2+chp
  const int chp = bx & 1;
  const int rg  = (bx >> 1) & 15;
  const int cg  = (bx >> 5) % 6;       // head
  const int b   = bx / 192;
  const int cl  = t >> 3;              // channel in head 0..31
  const int colgrp = t & 7;
  const int gc  = cg * 32 + cl;
  const int c0  = chp * 64 + colgrp * 8;
  const int r0  = rg * 8;
  const int bh  = b * NH + cg;
  const int l    = t & 63, w = t >> 6;
  const int arow = l & 15;
  const int koff = w * 32 + ((l >> 4) << 3);

  __shared__ __align__(16) u16 q_lds[32 * QLD];
  __shared__ __align__(16) u16 k_lds[32 * QLD];
  __shared__ __align__(16) u16 vt_lds[2 * 64 * VTS];
  __shared__ __align__(16) float gram_lds[1024];

  *(f32x4*)&gram_lds[t * 4] = (f32x4){0.f, 0.f, 0.f, 0.f};

  const float* __restrict__ xin = x + (((size_t)(b * CTOT + gc)) << 14);
  const float* __restrict__ yin = y + (((size_t)(b * CTOT + gc)) << 14);

  float wq[9], wk[9], wv[9];
#pragma unroll
  for (int i = 0; i < 9; ++i) {
    wq[i] = wdw[gc * 9 + i];
    wk[i] = wdw[(CTOT + gc) * 9 + i];
    wv[i] = wdw[(2 * CTOT + gc) * 9 + i];
  }

  float xb[3][10], yb[3][10];
  loadrow10(xb[0], xin, r0 - 1, c0);
  loadrow10(yb[0], yin, r0 - 1, c0);
  loadrow10(xb[1], xin, r0,     c0);
  loadrow10(yb[1], yin, r0,     c0);

  f32x4 acc[2][2] = {};
  float sq[2] = {0.f, 0.f}, sk[2] = {0.f, 0.f};

#pragma unroll
  for (int ph = 0; ph < 4; ++ph) {
#pragma unroll
    for (int sub = 0; sub < 2; ++sub) {
      const int rr = ph * 2 + sub;
      const int r  = r0 + rr;
      // ring-load the next input row (used as tap dr=2 this iteration)
      loadrow10(xb[(rr + 2) % 3], xin, r + 1, c0);
      loadrow10(yb[(rr + 2) % 3], yin, r + 1, c0);

      float aq[8], ak[8], av[8];
#pragma unroll
      for (int j = 0; j < 8; ++j) { aq[j] = 0.f; ak[j] = 0.f; av[j] = 0.f; }
#pragma unroll
      for (int dr = 0; dr < 3; ++dr) {
        const float* xr = xb[(rr + dr) % 3];
        const float* yr = yb[(rr + dr) % 3];
#pragma unroll
        for (int j = 0; j < 8; ++j)
#pragma unroll
          for (int dc = 0; dc < 3; ++dc) {
            aq[j] = fmaf(wq[dr * 3 + dc], xr[j + dc], aq[j]);
            ak[j] = fmaf(wk[dr * 3 + dc], yr[j + dc], ak[j]);
            av[j] = fmaf(wv[dr * 3 + dc], yr[j + dc], av[j]);
          }
      }
      short8 pq, pk;
#pragma unroll
      for (int j = 0; j < 8; ++j) {
        pq[j] = (short)f2bf(aq[j]);
        pk[j] = (short)f2bf(ak[j]);
      }
      *(short8*)&q_lds[cl * QLD + sub * 64 + colgrp * 8] = pq;
      *(short8*)&k_lds[cl * QLD + sub * 64 + colgrp * 8] = pk;
#pragma unroll
      for (int j = 0; j < 8; ++j)
        vt_lds[sub * 64 * VTS + (colgrp * 8 + j) * VTS + cl] = f2bf(av[j]);
    }
    __syncthreads();

    // gram partial via MFMA over the 128-pixel window + sum-of-squares
    short8 a2[2], b2[2];
#pragma unroll
    for (int tc = 0; tc < 2; ++tc) {
      a2[tc] = *(const short8*)&q_lds[(tc * 16 + arow) * QLD + koff];
      b2[tc] = *(const short8*)&k_lds[(tc * 16 + arow) * QLD + koff];
    }
#pragma unroll
    for (int tc = 0; tc < 2; ++tc)
#pragma unroll
      for (int j = 0; j < 8; ++j) {
        float fa = bf2f_s(a2[tc][j]); sq[tc] = fmaf(fa, fa, sq[tc]);
        float fb = bf2f_s(b2[tc][j]); sk[tc] = fmaf(fb, fb, sk[tc]);
      }
#pragma unroll
    for (int tc = 0; tc < 2; ++tc)
#pragma unroll
      for (int td = 0; td < 2; ++td)
        acc[tc][td] = __builtin_amdgcn_mfma_f32_16x16x32_bf16(a2[tc], b2[td], acc[tc][td], 0, 0, 0);

    // vt store: thread t owns (row sub=t>>7, col=(t>>1)&63, 16-ch half t&1)
    {
      const int sub  = t >> 7;
      const int col  = (t >> 1) & 63;
      const int half = (t & 1) * 16;
      const int r    = r0 + ph * 2 + sub;
      const int base = sub * 64 * VTS + col * VTS + half;
      short8 d0, d1;
#pragma unroll
      for (int j = 0; j < 8; ++j) { d0[j] = (short)vt_lds[base + j]; d1[j] = (short)vt_lds[base + 8 + j]; }
      size_t off = ((size_t)(b * HW + r * 128 + chp * 64 + col)) * CTOT + cg * 32 + half;
      *(short8*)(vt + off)     = d0;
      *(short8*)(vt + off + 8) = d1;
    }
    __syncthreads();
  }

  // block-level gram reduction in LDS, then one global atomicAdd per element
#pragma unroll
  for (int tc = 0; tc < 2; ++tc)
#pragma unroll
    for (int td = 0; td < 2; ++td)
#pragma unroll
      for (int r2 = 0; r2 < 4; ++r2) {
        int c = tc * 16 + (l >> 4) * 4 + r2;
        int d = td * 16 + arow;
        atomicAdd(&gram_lds[c * 32 + d], acc[tc][td][r2]);
      }
  __syncthreads();
#pragma unroll
  for (int i = 0; i < 4; ++i)
    atomicAdd(gram + (size_t)bh * 1024 + t * 4 + i, gram_lds[t * 4 + i]);

#pragma unroll
  for (int tc = 0; tc < 2; ++tc) {
    sq[tc] += __shfl_xor(sq[tc], 16);
    sq[tc] += __shfl_xor(sq[tc], 32);
    sk[tc] += __shfl_xor(sk[tc], 16);
    sk[tc] += __shfl_xor(sk[tc], 32);
  }
  if ((l >> 4) == 0) {
#pragma unroll
    for (int tc = 0; tc < 2; ++tc) {
      atomicAdd(sqq + bh * 32 + tc * 16 + arow, sq[tc]);
      atomicAdd(sqk + bh * 32 + tc * 16 + arow, sk[tc]);
    }
  }
}

// ---------------------------------------------------------------------------
// K2b: logits = gram/(|q||k|)*temp, row-softmax, fold 1x1 proj:
//   W2[b][o][h*32+d] = sum_c wp[o][h*32+c] * A[c][d]  (bf16 out)
// ---------------------------------------------------------------------------
__global__ __launch_bounds__(256) void k2b_w2(
    const float* __restrict__ gram, const float* __restrict__ sqq,
    const float* __restrict__ sqk, const float* __restrict__ wp,
    const float* __restrict__ temp, u16* __restrict__ W2)
{
  __shared__ float Ls[32][33];
  __shared__ float As[32][33];
  __shared__ float wl[192 * 32];
  __shared__ float nq[32], nk[32];
  const int t = threadIdx.x;
  const int bh = blockIdx.x, b = bh / 6, h = bh % 6;
  const float tmp = temp[h];
  if (t < 32) nq[t] = fmaxf(sqrtf(sqq[bh * 32 + t]), 1e-12f);
  else if (t < 64) nk[t - 32] = fmaxf(sqrtf(sqk[bh * 32 + t - 32]), 1e-12f);
  __syncthreads();
#pragma unroll
  for (int i = 0; i < 4; ++i) {
    int idx = i * 256 + t, c = idx >> 5, d = idx & 31;
    Ls[c][d] = gram[(size_t)bh * 1024 + idx] / (nq[c] * nk[d]) * tmp;
  }
  __syncthreads();
  if (t < 32) {
    float m = -1e30f;
#pragma unroll
    for (int d = 0; d < 32; ++d) m = fmaxf(m, Ls[t][d]);
    float s = 0.f;
#pragma unroll
    for (int d = 0; d < 32; ++d) s += expf(Ls[t][d] - m);
    float inv = 1.0f / s;
#pragma unroll
    for (int d = 0; d < 32; ++d) As[t][d] = expf(Ls[t][d] - m) * inv;
  }
  for (int i = 0; i < 24; ++i) {
    int idx = i * 256 + t, o = idx >> 5, c = idx & 31;
    wl[idx] = wp[o * 192 + h * 32 + c];
  }
  __syncthreads();
  for (int i = 0; i < 24; ++i) {
    int idx = i * 256 + t, o = idx >> 5, d = idx & 31;
    float a = 0.f;
#pragma unroll
    for (int c = 0; c < 32; ++c) a = fmaf(wl[o * 32 + c], As[c][d], a);
    W2[((size_t)(b * 192 + o)) * 192 + h * 32 + d] = f2bf(a);
  }
}

// ---------------------------------------------------------------------------
// K3: out[b][o][n] = sum_c W2[b][o][c] * v[b][c][n] via MFMA 16x16x32 bf16.
// A = W2 [o][c] k-contiguous, B = vt [n][c] k-contiguous: direct 16B loads.
// ---------------------------------------------------------------------------
__global__ __launch_bounds__(256) void k3_gemm(
    const u16* __restrict__ W2, const u16* __restrict__ vt,
    float* __restrict__ out)
{
  const int t = threadIdx.x, l = t & 63, w = t >> 6;
  const int bx = blockIdx.x;
  const int b  = bx >> 7, nb = bx & 127;
  const int row = l & 15;
  const int kq  = (l >> 4) * 8;
  const u16* w2b = W2 + (size_t)b * 192 * 192;
  const u16* vtb = vt + ((size_t)b << 14) * 192;
  const int n0 = nb * 128 + w * 32;

  f32x4 acc[12][2] = {};

  for (int ks = 0; ks < 6; ++ks) {
    const int kb = ks * 32 + kq;
    short8 bf[2];
#pragma unroll
    for (int nt = 0; nt < 2; ++nt)
      bf[nt] = *(const short8*)(vtb + (size_t)(n0 + nt * 16 + row) * 192 + kb);
#pragma unroll
    for (int ot = 0; ot < 12; ++ot) {
      short8 af = *(const short8*)(w2b + (size_t)(ot * 16 + row) * 192 + kb);
#pragma unroll
      for (int nt = 0; nt < 2; ++nt)
        acc[ot][nt] = __builtin_amdgcn_mfma_f32_16x16x32_bf16(af, bf[nt], acc[ot][nt], 0, 0, 0);
    }
  }

  float* ob = out + ((size_t)b * 192) * 16384;
#pragma unroll
  for (int ot = 0; ot < 12; ++ot)
#pragma unroll
    for (int nt = 0; nt < 2; ++nt)
#pragma unroll
      for (int rr = 0; rr < 4; ++rr) {
        int o = ot * 16 + (l >> 4) * 4 + rr;
        int n = n0 + nt * 16 + row;
        ob[(size_t)o * 16384 + n] = acc[ot][nt][rr];
      }
}

// ---------------------------------------------------------------------------
extern "C" void kernel_launch(void* const* d_in, const int* in_sizes, int n_in,
                              void* d_out, int out_size, void* d_ws, size_t ws_size,
                              hipStream_t stream)
{
  const float* x    = (const float*)d_in[0];
  const float* y    = (const float*)d_in[1];
  const float* wdw  = (const float*)d_in[2];
  const float* wp   = (const float*)d_in[3];
  const float* temp = (const float*)d_in[4];

  char* ws = (char*)d_ws;
  const size_t VT = (size_t)NB * HW * CTOT * 2;   // 50,331,648 bytes
  u16*   vt   = (u16*)(ws);
  float* gram = (float*)(ws + VT);                       // 48*1024*4 = 196608
  float* sqq  = (float*)(ws + VT + 196608);              // 6144
  float* sqk  = (float*)(ws + VT + 196608 + 6144);       // 6144
  u16*   W2   = (u16*)(ws + VT + 196608 + 12288);        // 8*192*192*2
  float* out  = (float*)d_out;

  hipMemsetAsync(ws + VT, 0, 208896, stream);
  k1_fused<<<1536, 256, 0, stream>>>(x, y, wdw, vt, gram, sqq, sqk);
  k2b_w2<<<48, 256, 0, stream>>>(gram, sqq, sqk, wp, temp, W2);
  k3_gemm<<<1024, 256, 0, stream>>>(W2, vt, out);
}

// Round 7
// 180.200 us; speedup vs baseline: 2.3420x; 1.0147x over previous
//
#include <hip/hip_runtime.h>
#include <hip/hip_bf16.h>

#define DEV __device__ __forceinline__

typedef unsigned short u16;
typedef unsigned int u32;
typedef __attribute__((ext_vector_type(8))) short short8;
typedef __attribute__((ext_vector_type(4))) float f32x4;

DEV u16 f2bf(float f) {
  __hip_bfloat16 h = __float2bfloat16(f);   // RNE; pairs into v_cvt_pk_bf16_f32
  return *(u16*)&h;
}
DEV float bf2f_s(short s) { return __uint_as_float(((u32)(u16)s) << 16); }

#define NB 8
#define NH 6
#define CTOT 192
#define HW 16384
#define QLD 136    // q/k LDS row stride (u16): 128-pixel K-window + 8 pad
#define VTS 34     // vt LDS per-col stride (u16): 32 ch + 2 pad

// load 10 input floats (8 outputs + 2 halo cols) of one row, zero-padded
DEV void loadrow10(float* d, const float* __restrict__ in, int ar, int c0) {
  const bool rok = (ar >= 0) && (ar < 128);
  const float* rp = in + ar * 128;
  d[0] = (rok && c0 > 0) ? rp[c0 - 1] : 0.0f;
  float4 f0, f1;
  if (rok) { f0 = *(const float4*)(rp + c0); f1 = *(const float4*)(rp + c0 + 4); }
  else { f0 = make_float4(0.f,0.f,0.f,0.f); f1 = f0; }
  d[1] = f0.x; d[2] = f0.y; d[3] = f0.z; d[4] = f0.w;
  d[5] = f1.x; d[6] = f1.y; d[7] = f1.z; d[8] = f1.w;
  d[9] = (rok && (c0 + 8) < 128) ? rp[c0 + 8] : 0.0f;
}

// ---------------------------------------------------------------------------
// K1 (fused, v4): round-6 structure + one-iteration-ahead load pipeline.
//  4-slot register row ring: iteration rr prefetches row r+2; the conv of
//  row r only touches rows loaded >= 1 full iteration ago, so HBM/L2 load
//  latency is covered by ~250 VALU ops of conv work instead of ~0.
//  Slot map: s(ar) = (ar - r0 + 1) & 3. Warmup fills s0..s2 (rows r0-1..r0+1).
// ---------------------------------------------------------------------------
__global__ __launch_bounds__(256) void k1_fused(
    const float* __restrict__ x, const float* __restrict__ y,
    const float* __restrict__ wdw,
    u16* __restrict__ vt, float* __restrict__ gram,
    float* __restrict__ sqq, float* __restrict__ sqk)
{
  const int t   = threadIdx.x;
  const int bx  = blockIdx.x;          // 1536 = ((b*6+cg)*16+rg)*2+chp
  const int chp = bx & 1;
  const int rg  = (bx >> 1) & 15;
  const int cg  = (bx >> 5) % 6;       // head
  const int b   = bx / 192;
  const int cl  = t >> 3;              // channel in head 0..31
  const int colgrp = t & 7;
  const int gc  = cg * 32 + cl;
  const int c0  = chp * 64 + colgrp * 8;
  const int r0  = rg * 8;
  const int bh  = b * NH + cg;
  const int l    = t & 63, w = t >> 6;
  const int arow = l & 15;
  const int koff = w * 32 + ((l >> 4) << 3);

  __shared__ __align__(16) u16 q_lds[32 * QLD];
  __shared__ __align__(16) u16 k_lds[32 * QLD];
  __shared__ __align__(16) u16 vt_lds[2 * 64 * VTS];
  __shared__ __align__(16) float gram_lds[1024];

  *(f32x4*)&gram_lds[t * 4] = (f32x4){0.f, 0.f, 0.f, 0.f};

  const float* __restrict__ xin = x + (((size_t)(b * CTOT + gc)) << 14);
  const float* __restrict__ yin = y + (((size_t)(b * CTOT + gc)) << 14);

  float wq[9], wk[9], wv[9];
#pragma unroll
  for (int i = 0; i < 9; ++i) {
    wq[i] = wdw[gc * 9 + i];
    wk[i] = wdw[(CTOT + gc) * 9 + i];
    wv[i] = wdw[(2 * CTOT + gc) * 9 + i];
  }

  float xb[4][10], yb[4][10];
  loadrow10(xb[0], xin, r0 - 1, c0);
  loadrow10(yb[0], yin, r0 - 1, c0);
  loadrow10(xb[1], xin, r0,     c0);
  loadrow10(yb[1], yin, r0,     c0);
  loadrow10(xb[2], xin, r0 + 1, c0);
  loadrow10(yb[2], yin, r0 + 1, c0);

  f32x4 acc[2][2] = {};
  float sq[2] = {0.f, 0.f}, sk[2] = {0.f, 0.f};

#pragma unroll
  for (int ph = 0; ph < 4; ++ph) {
#pragma unroll
    for (int sub = 0; sub < 2; ++sub) {
      const int rr = ph * 2 + sub;
      const int r  = r0 + rr;
      // prefetch row r+2 (one full iteration ahead of first use)
      if (rr < 7) {
        loadrow10(xb[(rr + 3) & 3], xin, r + 2, c0);
        loadrow10(yb[(rr + 3) & 3], yin, r + 2, c0);
      }

      float aq[8], ak[8], av[8];
#pragma unroll
      for (int j = 0; j < 8; ++j) { aq[j] = 0.f; ak[j] = 0.f; av[j] = 0.f; }
#pragma unroll
      for (int dr = 0; dr < 3; ++dr) {
        // (rr+dr)&3 is compile-time (fully unrolled) -> stays in registers
#pragma unroll
        for (int j = 0; j < 8; ++j)
#pragma unroll
          for (int dc = 0; dc < 3; ++dc) {
            aq[j] = fmaf(wq[dr * 3 + dc], xb[(rr + dr) & 3][j + dc], aq[j]);
            ak[j] = fmaf(wk[dr * 3 + dc], yb[(rr + dr) & 3][j + dc], ak[j]);
            av[j] = fmaf(wv[dr * 3 + dc], yb[(rr + dr) & 3][j + dc], av[j]);
          }
      }
      short8 pq, pk;
#pragma unroll
      for (int j = 0; j < 8; ++j) {
        pq[j] = (short)f2bf(aq[j]);
        pk[j] = (short)f2bf(ak[j]);
      }
      *(short8*)&q_lds[cl * QLD + sub * 64 + colgrp * 8] = pq;
      *(short8*)&k_lds[cl * QLD + sub * 64 + colgrp * 8] = pk;
#pragma unroll
      for (int j = 0; j < 8; ++j)
        vt_lds[sub * 64 * VTS + (colgrp * 8 + j) * VTS + cl] = f2bf(av[j]);
    }
    __syncthreads();

    // gram partial via MFMA over the 128-pixel window + sum-of-squares
    short8 a2[2], b2[2];
#pragma unroll
    for (int tc = 0; tc < 2; ++tc) {
      a2[tc] = *(const short8*)&q_lds[(tc * 16 + arow) * QLD + koff];
      b2[tc] = *(const short8*)&k_lds[(tc * 16 + arow) * QLD + koff];
    }
#pragma unroll
    for (int tc = 0; tc < 2; ++tc)
#pragma unroll
      for (int j = 0; j < 8; ++j) {
        float fa = bf2f_s(a2[tc][j]); sq[tc] = fmaf(fa, fa, sq[tc]);
        float fb = bf2f_s(b2[tc][j]); sk[tc] = fmaf(fb, fb, sk[tc]);
      }
#pragma unroll
    for (int tc = 0; tc < 2; ++tc)
#pragma unroll
      for (int td = 0; td < 2; ++td)
        acc[tc][td] = __builtin_amdgcn_mfma_f32_16x16x32_bf16(a2[tc], b2[td], acc[tc][td], 0, 0, 0);

    // vt store: thread t owns (row sub=t>>7, col=(t>>1)&63, 16-ch half t&1)
    {
      const int sub  = t >> 7;
      const int col  = (t >> 1) & 63;
      const int half = (t & 1) * 16;
      const int r    = r0 + ph * 2 + sub;
      const int base = sub * 64 * VTS + col * VTS + half;
      short8 d0, d1;
#pragma unroll
      for (int j = 0; j < 8; ++j) { d0[j] = (short)vt_lds[base + j]; d1[j] = (short)vt_lds[base + 8 + j]; }
      size_t off = ((size_t)(b * HW + r * 128 + chp * 64 + col)) * CTOT + cg * 32 + half;
      *(short8*)(vt + off)     = d0;
      *(short8*)(vt + off + 8) = d1;
    }
    __syncthreads();
  }

  // block-level gram reduction in LDS, then one global atomicAdd per element
#pragma unroll
  for (int tc = 0; tc < 2; ++tc)
#pragma unroll
    for (int td = 0; td < 2; ++td)
#pragma unroll
      for (int r2 = 0; r2 < 4; ++r2) {
        int c = tc * 16 + (l >> 4) * 4 + r2;
        int d = td * 16 + arow;
        atomicAdd(&gram_lds[c * 32 + d], acc[tc][td][r2]);
      }
  __syncthreads();
#pragma unroll
  for (int i = 0; i < 4; ++i)
    atomicAdd(gram + (size_t)bh * 1024 + t * 4 + i, gram_lds[t * 4 + i]);

#pragma unroll
  for (int tc = 0; tc < 2; ++tc) {
    sq[tc] += __shfl_xor(sq[tc], 16);
    sq[tc] += __shfl_xor(sq[tc], 32);
    sk[tc] += __shfl_xor(sk[tc], 16);
    sk[tc] += __shfl_xor(sk[tc], 32);
  }
  if ((l >> 4) == 0) {
#pragma unroll
    for (int tc = 0; tc < 2; ++tc) {
      atomicAdd(sqq + bh * 32 + tc * 16 + arow, sq[tc]);
      atomicAdd(sqk + bh * 32 + tc * 16 + arow, sk[tc]);
    }
  }
}

// ---------------------------------------------------------------------------
// K2b: logits = gram/(|q||k|)*temp, row-softmax, fold 1x1 proj:
//   W2[b][o][h*32+d] = sum_c wp[o][h*32+c] * A[c][d]  (bf16 out)
// ---------------------------------------------------------------------------
__global__ __launch_bounds__(256) void k2b_w2(
    const float* __restrict__ gram, const float* __restrict__ sqq,
    const float* __restrict__ sqk, const float* __restrict__ wp,
    const float* __restrict__ temp, u16* __restrict__ W2)
{
  __shared__ float Ls[32][33];
  __shared__ float As[32][33];
  __shared__ float wl[192 * 32];
  __shared__ float nq[32], nk[32];
  const int t = threadIdx.x;
  const int bh = blockIdx.x, b = bh / 6, h = bh % 6;
  const float tmp = temp[h];
  if (t < 32) nq[t] = fmaxf(sqrtf(sqq[bh * 32 + t]), 1e-12f);
  else if (t < 64) nk[t - 32] = fmaxf(sqrtf(sqk[bh * 32 + t - 32]), 1e-12f);
  __syncthreads();
#pragma unroll
  for (int i = 0; i < 4; ++i) {
    int idx = i * 256 + t, c = idx >> 5, d = idx & 31;
    Ls[c][d] = gram[(size_t)bh * 1024 + idx] / (nq[c] * nk[d]) * tmp;
  }
  __syncthreads();
  if (t < 32) {
    float m = -1e30f;
#pragma unroll
    for (int d = 0; d < 32; ++d) m = fmaxf(m, Ls[t][d]);
    float s = 0.f;
#pragma unroll
    for (int d = 0; d < 32; ++d) s += expf(Ls[t][d] - m);
    float inv = 1.0f / s;
#pragma unroll
    for (int d = 0; d < 32; ++d) As[t][d] = expf(Ls[t][d] - m) * inv;
  }
  for (int i = 0; i < 24; ++i) {
    int idx = i * 256 + t, o = idx >> 5, c = idx & 31;
    wl[idx] = wp[o * 192 + h * 32 + c];
  }
  __syncthreads();
  for (int i = 0; i < 24; ++i) {
    int idx = i * 256 + t, o = idx >> 5, d = idx & 31;
    float a = 0.f;
#pragma unroll
    for (int c = 0; c < 32; ++c) a = fmaf(wl[o * 32 + c], As[c][d], a);
    W2[((size_t)(b * 192 + o)) * 192 + h * 32 + d] = f2bf(a);
  }
}

// ---------------------------------------------------------------------------
// K3: out[b][o][n] = sum_c W2[b][o][c] * v[b][c][n] via MFMA 16x16x32 bf16.
// A = W2 [o][c] k-contiguous, B = vt [n][c] k-contiguous: direct 16B loads.
// ---------------------------------------------------------------------------
__global__ __launch_bounds__(256) void k3_gemm(
    const u16* __restrict__ W2, const u16* __restrict__ vt,
    float* __restrict__ out)
{
  const int t = threadIdx.x, l = t & 63, w = t >> 6;
  const int bx = blockIdx.x;
  const int b  = bx >> 7, nb = bx & 127;
  const int row = l & 15;
  const int kq  = (l >> 4) * 8;
  const u16* w2b = W2 + (size_t)b * 192 * 192;
  const u16* vtb = vt + ((size_t)b << 14) * 192;
  const int n0 = nb * 128 + w * 32;

  f32x4 acc[12][2] = {};

  for (int ks = 0; ks < 6; ++ks) {
    const int kb = ks * 32 + kq;
    short8 bf[2];
#pragma unroll
    for (int nt = 0; nt < 2; ++nt)
      bf[nt] = *(const short8*)(vtb + (size_t)(n0 + nt * 16 + row) * 192 + kb);
#pragma unroll
    for (int ot = 0; ot < 12; ++ot) {
      short8 af = *(const short8*)(w2b + (size_t)(ot * 16 + row) * 192 + kb);
#pragma unroll
      for (int nt = 0; nt < 2; ++nt)
        acc[ot][nt] = __builtin_amdgcn_mfma_f32_16x16x32_bf16(af, bf[nt], acc[ot][nt], 0, 0, 0);
    }
  }

  float* ob = out + ((size_t)b * 192) * 16384;
#pragma unroll
  for (int ot = 0; ot < 12; ++ot)
#pragma unroll
    for (int nt = 0; nt < 2; ++nt)
#pragma unroll
      for (int rr = 0; rr < 4; ++rr) {
        int o = ot * 16 + (l >> 4) * 4 + rr;
        int n = n0 + nt * 16 + row;
        ob[(size_t)o * 16384 + n] = acc[ot][nt][rr];
      }
}

// ---------------------------------------------------------------------------
extern "C" void kernel_launch(void* const* d_in, const int* in_sizes, int n_in,
                              void* d_out, int out_size, void* d_ws, size_t ws_size,
                              hipStream_t stream)
{
  const float* x    = (const float*)d_in[0];
  const float* y    = (const float*)d_in[1];
  const float* wdw  = (const float*)d_in[2];
  const float* wp   = (const float*)d_in[3];
  const float* temp = (const float*)d_in[4];

  char* ws = (char*)d_ws;
  const size_t VT = (size_t)NB * HW * CTOT * 2;   // 50,331,648 bytes
  u16*   vt   = (u16*)(ws);
  float* gram = (float*)(ws + VT);                       // 48*1024*4 = 196608
  float* sqq  = (float*)(ws + VT + 196608);              // 6144
  float* sqk  = (float*)(ws + VT + 196608 + 6144);       // 6144
  u16*   W2   = (u16*)(ws + VT + 196608 + 12288);        // 8*192*192*2
  float* out  = (float*)d_out;

  hipMemsetAsync(ws + VT, 0, 208896, stream);
  k1_fused<<<1536, 256, 0, stream>>>(x, y, wdw, vt, gram, sqq, sqk);
  k2b_w2<<<48, 256, 0, stream>>>(gram, sqq, sqk, wp, temp, W2);
  k3_gemm<<<1024, 256, 0, stream>>>(W2, vt, out);
}